// Round 10
// baseline (256.238 us; speedup 1.0000x reference)
//
#include <hip/hip_runtime.h>
#include <hip/hip_bf16.h>

#define LOG2E 1.4426950408889634f
// reference: mask(-1e9) BEFORE scale(/8); we also fold log2e into Q/K product
#define MASKVAL (-1.25e8f * LOG2E)

typedef __bf16 bf16x8 __attribute__((ext_vector_type(8)));
typedef __bf16 bf16x4 __attribute__((ext_vector_type(4)));
typedef short  shortx4 __attribute__((ext_vector_type(4)));
typedef float  floatx4 __attribute__((ext_vector_type(4)));

__device__ __forceinline__ floatx4 mfma16(bf16x8 a, bf16x8 b, floatx4 c) {
  return __builtin_amdgcn_mfma_f32_16x16x32_bf16(a, b, c, 0, 0, 0);
}

// 16x16x16 bf16 MFMA: B-operand layout (n=l15, k=quad*4+i) == S^T C-tile
// layout, so P feeds PV with ZERO cross-lane transforms.
__device__ __forceinline__ floatx4 mfma_pv(bf16x4 a, bf16x4 b, floatx4 c) {
#if __has_builtin(__builtin_amdgcn_mfma_f32_16x16x16_bf16)
  return __builtin_amdgcn_mfma_f32_16x16x16_bf16(a, b, c, 0, 0, 0);
#else
  shortx4 as, bs;
  __builtin_memcpy(&as, &a, 8);
  __builtin_memcpy(&bs, &b, 8);
  return __builtin_amdgcn_mfma_f32_16x16x16bf16_1k(as, bs, c, 0, 0, 0);
#endif
}

// async global->LDS, 16B per lane. Dest = wave-uniform base + lane*16.
__device__ __forceinline__ void load_lds16(const __bf16* g, __bf16* l) {
  __builtin_amdgcn_global_load_lds(
      (const __attribute__((address_space(1))) void*)g,
      (__attribute__((address_space(3))) void*)l, 16, 0, 0);
}

// ---------------------------------------------------------------------------
// Fold LoRA into weights, emit W_eff^T bf16 [ncols][1024].  Both weight sets
// in one launch: blockIdx.x < 48 -> qkv (ncols 3072), else proj (ncols 1024).
// ---------------------------------------------------------------------------
__global__ __launch_bounds__(256)
void fold_wt2(const float* __restrict__ Wq, const float* __restrict__ Aq,
              const float* __restrict__ Bq, __bf16* __restrict__ WTq,
              const float* __restrict__ Wp, const float* __restrict__ Ap,
              const float* __restrict__ Bp, __bf16* __restrict__ WTp) {
  __shared__ float tile[64][65];
  __shared__ float sLb[8][64];
  const int bx = blockIdx.x;
  const bool isQ = bx < 48;
  const float* W  = isQ ? Wq : Wp;
  const float* La = isQ ? Aq : Ap;
  const float* Lb = isQ ? Bq : Bp;
  __bf16* WT = isQ ? WTq : WTp;
  const int ncols = isQ ? 3072 : 1024;
  const int nt = (isQ ? bx : bx - 48) * 64;
  const int kt = blockIdx.y * 64;
  const int tid = threadIdx.x;
  const int tx = tid & 63, ty = tid >> 6;

  float rLa[8];
  *(float4*)&rLa[0] = *(const float4*)(La + (size_t)(kt + tx) * 8);
  *(float4*)&rLa[4] = *(const float4*)(La + (size_t)(kt + tx) * 8 + 4);

#pragma unroll
  for (int rep = 0; rep < 2; rep++) {
    int idx = tid + rep * 256;
    sLb[idx >> 6][idx & 63] = Lb[(size_t)(idx >> 6) * ncols + nt + (idx & 63)];
  }
#pragma unroll
  for (int rep = 0; rep < 16; rep++) {
    int i = rep * 4 + ty;
    tile[i][tx] = W[(size_t)(kt + i) * ncols + nt + tx];
  }
  __syncthreads();
#pragma unroll
  for (int rep = 0; rep < 16; rep++) {
    int i = rep * 4 + ty;
    int n = nt + i, k = kt + tx;
    float acc = tile[tx][i];
#pragma unroll
    for (int r = 0; r < 8; r++)
      acc += 2.0f * rLa[r] * sLb[r][i];  // LORA_SCALING = 2
    WT[(size_t)n * 1024 + k] = (__bf16)acc;
  }
}

__global__ __launch_bounds__(256)
void cast_x(const float* __restrict__ x, __bf16* __restrict__ o) {
  int i = blockIdx.x * 256 + threadIdx.x;
  float4 v = ((const float4*)x)[i];
  bf16x4 r = {(__bf16)v.x, (__bf16)v.y, (__bf16)v.z, (__bf16)v.w};
  ((bf16x4*)o)[i] = r;
}

// ---------------------------------------------------------------------------
// Fused QKV projection, swapped orientation: D[p][s] = sum_k WT[p][k] X[s][k].
// 128x128 tiles, BK=64, global_load_lds staging, XOR-swizzled LDS.
// Q channels (p<1024) pre-scaled by 0.125*LOG2E (score scale + log2-domain
// softmax fold); flash does exp2 with no per-score multiply.
// ---------------------------------------------------------------------------
__global__ __launch_bounds__(256)
void gemm_qkv(const __bf16* __restrict__ WT, const __bf16* __restrict__ X,
              const float* __restrict__ bias, __bf16* __restrict__ qk,
              __bf16* __restrict__ vtb) {
  const int K = 1024;
  __shared__ alignas(16) __bf16 As[128 * 64];
  __shared__ alignas(16) __bf16 Bs[128 * 64];
  const int tid = threadIdx.x;
  const int wave = tid >> 6, lane = tid & 63;
  const int wm = wave >> 1, wn = wave & 1;
  const int quad = lane >> 4, l15 = lane & 15;
  const int p0 = blockIdx.y * 128, s0 = blockIdx.x * 128;
  const int srow8 = lane >> 3, sc8 = lane & 7;
  const int sswz = sc8 ^ srow8;

  floatx4 acc[4][4] = {};

  for (int kb = 0; kb < K; kb += 64) {
    __syncthreads();
#pragma unroll
    for (int t = 0; t < 4; t++) {
      int rbase = (wave * 4 + t) * 8;
      int row = rbase + srow8;
      load_lds16(WT + (size_t)(p0 + row) * K + kb + sswz * 8, As + rbase * 64);
      load_lds16(X + (size_t)(s0 + row) * K + kb + sswz * 8, Bs + rbase * 64);
    }
    __syncthreads();
#pragma unroll
    for (int ks = 0; ks < 2; ks++) {
      bf16x8 af[4], bfv[4];
#pragma unroll
      for (int t = 0; t < 4; t++) {
        int ra = wm * 64 + t * 16 + l15;
        int rb = wn * 64 + t * 16 + l15;
        int ch = (ks * 4 + quad) ^ (l15 & 7);
        af[t]  = *(const bf16x8*)(As + ra * 64 + ch * 8);
        bfv[t] = *(const bf16x8*)(Bs + rb * 64 + ch * 8);
      }
#pragma unroll
      for (int mi = 0; mi < 4; mi++)
#pragma unroll
        for (int ni = 0; ni < 4; ni++)
          acc[mi][ni] = mfma16(af[mi], bfv[ni], acc[mi][ni]);
    }
  }

  const float qscale = (p0 < 1024) ? 0.125f * LOG2E : 1.0f;  // block-uniform
#pragma unroll
  for (int mi = 0; mi < 4; mi++) {
#pragma unroll
    for (int ni = 0; ni < 4; ni++) {
      int pb = p0 + wm * 64 + mi * 16 + quad * 4;  // channel base (mult of 4)
      int s  = s0 + wn * 64 + ni * 16 + l15;       // token
      int b = s >> 11, s2 = s & 2047;
      if (p0 < 2048) {  // q/k: uniform per block
        int part = pb >> 10, h = (pb & 1023) >> 6, dhb = pb & 63;
        bf16x4 o = {(__bf16)((acc[mi][ni][0] + bias[pb]) * qscale),
                    (__bf16)((acc[mi][ni][1] + bias[pb + 1]) * qscale),
                    (__bf16)((acc[mi][ni][2] + bias[pb + 2]) * qscale),
                    (__bf16)((acc[mi][ni][3] + bias[pb + 3]) * qscale)};
        *(bf16x4*)(qk + (size_t)part * 4194304 +
                   ((size_t)((b * 16 + h) * 2048 + s2)) * 64 + dhb) = o;
      } else {  // v -> v^T
        int h = (pb & 1023) >> 6, dhb = pb & 63;
#pragma unroll
        for (int r = 0; r < 4; r++)
          vtb[((size_t)((b * 16 + h) * 64 + dhb + r)) * 2048 + s2] =
              (__bf16)(acc[mi][ni][r] + bias[pb + r]);
      }
    }
  }
}

// ---------------------------------------------------------------------------
// Output projection, 64x128 tile: grid (8, 64) = 512 blocks.  fp32 out + bias.
// ---------------------------------------------------------------------------
__global__ __launch_bounds__(256)
void gemm_proj(const __bf16* __restrict__ A, const __bf16* __restrict__ BT,
               const float* __restrict__ bias, float* __restrict__ Cout, int N) {
  const int K = 1024;
  __shared__ alignas(16) __bf16 As[64 * 64];
  __shared__ alignas(16) __bf16 Bs[128 * 64];
  const int tid = threadIdx.x;
  const int wave = tid >> 6, lane = tid & 63;
  const int wm = wave >> 1, wn = wave & 1;
  const int quad = lane >> 4, l15 = lane & 15;
  const int m0 = blockIdx.y * 64, n0 = blockIdx.x * 128;
  const int srow8 = lane >> 3, sc8 = lane & 7;
  const int sswz = sc8 ^ srow8;

  floatx4 acc[2][4] = {};

  for (int kb = 0; kb < K; kb += 64) {
    __syncthreads();
#pragma unroll
    for (int t = 0; t < 2; t++) {
      int rbase = (wave * 2 + t) * 8;
      load_lds16(A + (size_t)(m0 + rbase + srow8) * K + kb + sswz * 8,
                 As + rbase * 64);
    }
#pragma unroll
    for (int t = 0; t < 4; t++) {
      int rbase = (wave * 4 + t) * 8;
      load_lds16(BT + (size_t)(n0 + rbase + srow8) * K + kb + sswz * 8,
                 Bs + rbase * 64);
    }
    __syncthreads();
#pragma unroll
    for (int ks = 0; ks < 2; ks++) {
      bf16x8 af[2], bfv[4];
      int ch = (ks * 4 + quad) ^ (l15 & 7);
#pragma unroll
      for (int t = 0; t < 2; t++)
        af[t] = *(const bf16x8*)(As + (wm * 32 + t * 16 + l15) * 64 + ch * 8);
#pragma unroll
      for (int t = 0; t < 4; t++)
        bfv[t] = *(const bf16x8*)(Bs + (wn * 64 + t * 16 + l15) * 64 + ch * 8);
#pragma unroll
      for (int mi = 0; mi < 2; mi++)
#pragma unroll
        for (int ni = 0; ni < 4; ni++)
          acc[mi][ni] = mfma16(af[mi], bfv[ni], acc[mi][ni]);
    }
  }

#pragma unroll
  for (int mi = 0; mi < 2; mi++)
#pragma unroll
    for (int ni = 0; ni < 4; ni++) {
      int n = n0 + wn * 64 + ni * 16 + l15;
#pragma unroll
      for (int r = 0; r < 4; r++) {
        int m = m0 + wm * 32 + mi * 16 + quad * 4 + r;
        Cout[(size_t)m * N + n] = acc[mi][ni][r] + bias[n];
      }
    }
}

// ---------------------------------------------------------------------------
// Causal flash attention v9: split-K x4, shuffle-free PV.
// Block = 4 waves = one 32-q strip; wave w takes 64-key chunks w, w+4, ...
// S^T = K·Q^T (16x16x32): C col(l15)=q, row(quad*4+r)=key.
// PV as O^T = V^T·P^T via 16x16x16 MFMA: P^T's C-layout IS the B-operand
// layout (n=l15=q, k=quad*4+i=key) -> zero cross-lane transforms; O^T has
// q on l15 so alpha/l/merge factors are all lane-local.
// Q pre-scaled by 0.125*LOG2E (log2-domain softmax); mask = -1.25e8*LOG2E.
// NO second __launch_bounds__ arg (R4/R7: waves/EU hint -> spills).
// ---------------------------------------------------------------------------
__global__ __launch_bounds__(256)
void flash_attn(const __bf16* __restrict__ q, const __bf16* __restrict__ k,
                const __bf16* __restrict__ vt, const int* __restrict__ amask,
                __bf16* __restrict__ ctx) {
  const int S = 2048;
  __shared__ float mbuf[3][36][64];  // [wave-1][elem][lane], conflict-free
  const int bid = blockIdx.x;
  const int wave = threadIdx.x >> 6, lane = threadIdx.x & 63;
  const int j = 63 - (bid >> 5);               // strip, heaviest first
  const int bh = (bid & 7) * 4 + ((bid >> 3) & 3);
  const int b = bh >> 4, h = bh & 15;
  const int quad = lane >> 4, l15 = lane & 15;
  const int q0 = j * 32;

  const __bf16* qp  = q  + (size_t)bh * S * 64;
  const __bf16* kp0 = k  + (size_t)bh * S * 64;
  const __bf16* vp0 = vt + (size_t)bh * 64 * S;

  bf16x8 qf[2][2];  // [mt][ks]
#pragma unroll
  for (int mt = 0; mt < 2; mt++)
#pragma unroll
    for (int ks = 0; ks < 2; ks++)
      qf[mt][ks] = *(const bf16x8*)(qp + (size_t)(q0 + mt * 16 + l15) * 64 +
                                    ks * 32 + quad * 8);

  float mrun[2] = {-1.0e30f, -1.0e30f}, lrun[2] = {0.0f, 0.0f};
  floatx4 oacc[2][4] = {};  // [mt][dh-tile]; col(l15)=q, row(quad*4+r)=dh
  const int nch = ((q0 + 31) >> 6) + 1;  // 64-key chunks

  for (int c = wave; c < nch; c += 4) {
    const __bf16* kp = kp0 + (size_t)c * 64 * 64;
    floatx4 st[4][2] = {};  // [key-tile][q-tile]; col(l15)=q, row(quad*4+r)=key
#pragma unroll
    for (int ks = 0; ks < 2; ks++) {
      bf16x8 kf[4];
#pragma unroll
      for (int nt = 0; nt < 4; nt++)
        kf[nt] = *(const bf16x8*)(kp + (size_t)(nt * 16 + l15) * 64 +
                                  ks * 32 + quad * 8);
#pragma unroll
      for (int nt = 0; nt < 4; nt++) {
        st[nt][0] = mfma16(kf[nt], qf[0][ks], st[nt][0]);
        st[nt][1] = mfma16(kf[nt], qf[1][ks], st[nt][1]);
      }
    }
    unsigned long long pm = __ballot(amask[b * S + c * 64 + lane] == 0);

    if (c == nch - 1) {  // wave-uniform: only the diagonal chunk needs causal
#pragma unroll
      for (int nt = 0; nt < 4; nt++) {
        int kl = nt * 16 + quad * 4;
        int keyg = c * 64 + kl;
#pragma unroll
        for (int r = 0; r < 4; r++) {
          bool pad = (pm >> (kl + r)) & 1ull;
#pragma unroll
          for (int mt = 0; mt < 2; mt++) {
            bool masked = pad || (keyg + r > q0 + mt * 16 + l15);
            st[nt][mt][r] = masked ? MASKVAL : st[nt][mt][r];
          }
        }
      }
    } else {
#pragma unroll
      for (int nt = 0; nt < 4; nt++) {
        int kl = nt * 16 + quad * 4;
#pragma unroll
        for (int r = 0; r < 4; r++) {
          bool pad = (pm >> (kl + r)) & 1ull;
#pragma unroll
          for (int mt = 0; mt < 2; mt++)
            st[nt][mt][r] = pad ? MASKVAL : st[nt][mt][r];
        }
      }
    }

    // online softmax in log2 domain (per q = l15), tree reductions
    float al[2];
#pragma unroll
    for (int mt = 0; mt < 2; mt++) {
      float m4[4];
#pragma unroll
      for (int nt = 0; nt < 4; nt++)
        m4[nt] = fmaxf(fmaxf(st[nt][mt][0], st[nt][mt][1]),
                       fmaxf(st[nt][mt][2], st[nt][mt][3]));
      float rm = fmaxf(fmaxf(m4[0], m4[1]), fmaxf(m4[2], m4[3]));
      rm = fmaxf(rm, __shfl_xor(rm, 16, 64));
      rm = fmaxf(rm, __shfl_xor(rm, 32, 64));
      float mnew = fmaxf(mrun[mt], rm);
      al[mt] = exp2f(mrun[mt] - mnew);
      mrun[mt] = mnew;
      float s4[4];
#pragma unroll
      for (int nt = 0; nt < 4; nt++) {
        float p0 = exp2f(st[nt][mt][0] - mnew);
        float p1 = exp2f(st[nt][mt][1] - mnew);
        float p2 = exp2f(st[nt][mt][2] - mnew);
        float p3 = exp2f(st[nt][mt][3] - mnew);
        st[nt][mt][0] = p0; st[nt][mt][1] = p1;
        st[nt][mt][2] = p2; st[nt][mt][3] = p3;
        s4[nt] = (p0 + p1) + (p2 + p3);
      }
      float rs = (s4[0] + s4[1]) + (s4[2] + s4[3]);
      rs += __shfl_xor(rs, 16, 64);
      rs += __shfl_xor(rs, 32, 64);
      lrun[mt] = lrun[mt] * al[mt] + rs;
    }

    // rescale O: alpha per q = l15 -> lane-local (no shuffles)
#pragma unroll
    for (int mt = 0; mt < 2; mt++)
#pragma unroll
      for (int nd = 0; nd < 4; nd++)
#pragma unroll
        for (int r = 0; r < 4; r++) oacc[mt][nd][r] *= al[mt];

    // O^T += V^T P^T : pack P tile (B-operand == C-layout) and 16x16x16 MFMA
#pragma unroll
    for (int nt = 0; nt < 4; nt++) {
      bf16x4 pB0 = {(__bf16)st[nt][0][0], (__bf16)st[nt][0][1],
                    (__bf16)st[nt][0][2], (__bf16)st[nt][0][3]};
      bf16x4 pB1 = {(__bf16)st[nt][1][0], (__bf16)st[nt][1][1],
                    (__bf16)st[nt][1][2], (__bf16)st[nt][1][3]};
      const __bf16* vp = vp0 + c * 64 + nt * 16 + quad * 4;
#pragma unroll
      for (int nd = 0; nd < 4; nd++) {
        bf16x4 vA = *(const bf16x4*)(vp + (size_t)(nd * 16 + l15) * S);
        oacc[0][nd] = mfma_pv(vA, pB0, oacc[0][nd]);
        oacc[1][nd] = mfma_pv(vA, pB1, oacc[1][nd]);
      }
    }
  }

  // ---- split-K merge: waves 1-3 publish (O, m, l); wave 0 combines ----
  if (wave != 0) {
    int w = wave - 1;
#pragma unroll
    for (int mt = 0; mt < 2; mt++)
#pragma unroll
      for (int nd = 0; nd < 4; nd++)
#pragma unroll
        for (int r = 0; r < 4; r++)
          mbuf[w][(mt * 4 + nd) * 4 + r][lane] = oacc[mt][nd][r];
#pragma unroll
    for (int mt = 0; mt < 2; mt++) {
      mbuf[w][32 + mt][lane] = mrun[mt];
      mbuf[w][34 + mt][lane] = lrun[mt];
    }
  }
  __syncthreads();
  if (wave != 0) return;

  // combine factors per q = l15 (lane-local; log2 domain)
  float fw[3][2], f0[2], lstar[2];
#pragma unroll
  for (int mt = 0; mt < 2; mt++) {
    float mw0 = mbuf[0][32 + mt][lane], lw0 = mbuf[0][34 + mt][lane];
    float mw1 = mbuf[1][32 + mt][lane], lw1 = mbuf[1][34 + mt][lane];
    float mw2 = mbuf[2][32 + mt][lane], lw2 = mbuf[2][34 + mt][lane];
    float mstar = fmaxf(fmaxf(mrun[mt], mw0), fmaxf(mw1, mw2));
    f0[mt] = exp2f(mrun[mt] - mstar);
    fw[0][mt] = exp2f(mw0 - mstar);
    fw[1][mt] = exp2f(mw1 - mstar);
    fw[2][mt] = exp2f(mw2 - mstar);
    lstar[mt] = f0[mt] * lrun[mt] + fw[0][mt] * lw0 + fw[1][mt] * lw1 +
                fw[2][mt] * lw2;
    lstar[mt] = 1.0f / lstar[mt];
  }

  // epilogue: lane l15 = q, rows quad*4+r = dh -> packed b64 stores
#pragma unroll
  for (int mt = 0; mt < 2; mt++) {
    int s = q0 + mt * 16 + l15;
#pragma unroll
    for (int nd = 0; nd < 4; nd++) {
      float ov[4];
#pragma unroll
      for (int r = 0; r < 4; r++) {
        float v = f0[mt] * oacc[mt][nd][r];
#pragma unroll
        for (int w = 0; w < 3; w++)
          v += fw[w][mt] * mbuf[w][(mt * 4 + nd) * 4 + r][lane];
        ov[r] = v * lstar[mt];
      }
      bf16x4 o = {(__bf16)ov[0], (__bf16)ov[1], (__bf16)ov[2], (__bf16)ov[3]};
      *(bf16x4*)(ctx + ((size_t)(b * 2048 + s)) * 1024 + h * 64 + nd * 16 +
                 quad * 4) = o;
    }
  }
}

// ---------------------------------------------------------------------------
extern "C" void kernel_launch(void* const* d_in, const int* in_sizes, int n_in,
                              void* d_out, int out_size, void* d_ws, size_t ws_size,
                              hipStream_t stream) {
  const float* x  = (const float*)d_in[0];
  const int*   am = (const int*)d_in[1];
  const float* Wq = (const float*)d_in[2];
  const float* bq = (const float*)d_in[3];
  const float* Aq = (const float*)d_in[4];
  const float* Bq = (const float*)d_in[5];
  const float* Wp = (const float*)d_in[6];
  const float* bp = (const float*)d_in[7];
  const float* Ap = (const float*)d_in[8];
  const float* Bp = (const float*)d_in[9];

  __bf16* wqkvT = (__bf16*)d_ws;                       // [3072][1024]
  __bf16* wpT   = wqkvT + (size_t)3072 * 1024;         // [1024][1024]
  __bf16* xbf   = wpT   + (size_t)1024 * 1024;         // [4096][1024]
  __bf16* qbuf  = xbf   + (size_t)4096 * 1024;         // [2][16][2048][64] (+kbuf)
  __bf16* vtbuf = qbuf  + (size_t)2 * 4194304;         // [2][16][64][2048]
  __bf16* ctxb  = vtbuf + (size_t)4194304;             // [4096][1024]

  fold_wt2<<<dim3(64, 16), 256, 0, stream>>>(Wq, Aq, Bq, wqkvT,
                                             Wp, Ap, Bp, wpT);
  cast_x<<<4096, 256, 0, stream>>>(x, xbf);

  gemm_qkv<<<dim3(32, 24), 256, 0, stream>>>(wqkvT, xbf, bq, qbuf, vtbuf);
  flash_attn<<<2048, 256, 0, stream>>>(qbuf, qbuf + 4194304, vtbuf, am, ctxb);
  gemm_proj<<<dim3(8, 64), 256, 0, stream>>>(ctxb, wpT, bp, (float*)d_out, 1024);
}

// Round 11
// 232.626 us; speedup vs baseline: 1.1015x; 1.1015x over previous
//
#include <hip/hip_runtime.h>
#include <hip/hip_bf16.h>

#define LOG2E 1.4426950408889634f
// reference: mask(-1e9) BEFORE scale(/8); log2e folded into Q pre-scale
#define MASKVAL (-1.25e8f * LOG2E)

typedef __bf16 bf16x8 __attribute__((ext_vector_type(8)));
typedef __bf16 bf16x4 __attribute__((ext_vector_type(4)));
typedef short  shortx4 __attribute__((ext_vector_type(4)));
typedef float  floatx4 __attribute__((ext_vector_type(4)));

__device__ __forceinline__ floatx4 mfma16(bf16x8 a, bf16x8 b, floatx4 c) {
  return __builtin_amdgcn_mfma_f32_16x16x32_bf16(a, b, c, 0, 0, 0);
}

// 16x16x16 bf16 MFMA: B-operand layout (n=l15, k=quad*4+i) == S^T C-tile
// layout -> P feeds PV with zero cross-lane transforms.
__device__ __forceinline__ floatx4 mfma_pv(bf16x4 a, bf16x4 b, floatx4 c) {
#if __has_builtin(__builtin_amdgcn_mfma_f32_16x16x16_bf16)
  return __builtin_amdgcn_mfma_f32_16x16x16_bf16(a, b, c, 0, 0, 0);
#else
  shortx4 as, bs;
  __builtin_memcpy(&as, &a, 8);
  __builtin_memcpy(&bs, &b, 8);
  return __builtin_amdgcn_mfma_f32_16x16x16bf16_1k(as, bs, c, 0, 0, 0);
#endif
}

// async global->LDS, 16B per lane. Dest = wave-uniform base + lane*16.
__device__ __forceinline__ void load_lds16(const __bf16* g, __bf16* l) {
  __builtin_amdgcn_global_load_lds(
      (const __attribute__((address_space(1))) void*)g,
      (__attribute__((address_space(3))) void*)l, 16, 0, 0);
}

// ---------------------------------------------------------------------------
// Fold LoRA into weights, emit W_eff^T bf16 [ncols][1024].  Both weight sets
// in one launch: blockIdx.x < 48 -> qkv (ncols 3072), else proj (ncols 1024).
// ---------------------------------------------------------------------------
__global__ __launch_bounds__(256)
void fold_wt2(const float* __restrict__ Wq, const float* __restrict__ Aq,
              const float* __restrict__ Bq, __bf16* __restrict__ WTq,
              const float* __restrict__ Wp, const float* __restrict__ Ap,
              const float* __restrict__ Bp, __bf16* __restrict__ WTp) {
  __shared__ float tile[64][65];
  __shared__ float sLb[8][64];
  const int bx = blockIdx.x;
  const bool isQ = bx < 48;
  const float* W  = isQ ? Wq : Wp;
  const float* La = isQ ? Aq : Ap;
  const float* Lb = isQ ? Bq : Bp;
  __bf16* WT = isQ ? WTq : WTp;
  const int ncols = isQ ? 3072 : 1024;
  const int nt = (isQ ? bx : bx - 48) * 64;
  const int kt = blockIdx.y * 64;
  const int tid = threadIdx.x;
  const int tx = tid & 63, ty = tid >> 6;

  float rLa[8];
  *(float4*)&rLa[0] = *(const float4*)(La + (size_t)(kt + tx) * 8);
  *(float4*)&rLa[4] = *(const float4*)(La + (size_t)(kt + tx) * 8 + 4);

#pragma unroll
  for (int rep = 0; rep < 2; rep++) {
    int idx = tid + rep * 256;
    sLb[idx >> 6][idx & 63] = Lb[(size_t)(idx >> 6) * ncols + nt + (idx & 63)];
  }
#pragma unroll
  for (int rep = 0; rep < 16; rep++) {
    int i = rep * 4 + ty;
    tile[i][tx] = W[(size_t)(kt + i) * ncols + nt + tx];
  }
  __syncthreads();
#pragma unroll
  for (int rep = 0; rep < 16; rep++) {
    int i = rep * 4 + ty;
    int n = nt + i, k = kt + tx;
    float acc = tile[tx][i];
#pragma unroll
    for (int r = 0; r < 8; r++)
      acc += 2.0f * rLa[r] * sLb[r][i];  // LORA_SCALING = 2
    WT[(size_t)n * 1024 + k] = (__bf16)acc;
  }
}

__global__ __launch_bounds__(256)
void cast_x(const float* __restrict__ x, __bf16* __restrict__ o) {
  int i = blockIdx.x * 256 + threadIdx.x;
  float4 v = ((const float4*)x)[i];
  bf16x4 r = {(__bf16)v.x, (__bf16)v.y, (__bf16)v.z, (__bf16)v.w};
  ((bf16x4*)o)[i] = r;
}

// ---------------------------------------------------------------------------
// Fused QKV projection, swapped orientation: D[p][s] = sum_k WT[p][k] X[s][k].
// 128x128 tiles, BK=64, global_load_lds staging, XOR-swizzled LDS.
// Q channels (p<1024) pre-scaled by 0.125*LOG2E.
// V is written to vtb with keys PERMUTED within each 64-key chunk so the
// flash PV A-fragments are 16B-contiguous: key off (t=off>>4, qd=(off>>2)&3,
// r=off&3) stored at position (t>>1)*32 + qd*8 + (t&1)*4 + r.
// ---------------------------------------------------------------------------
__global__ __launch_bounds__(256)
void gemm_qkv(const __bf16* __restrict__ WT, const __bf16* __restrict__ X,
              const float* __restrict__ bias, __bf16* __restrict__ qk,
              __bf16* __restrict__ vtb) {
  const int K = 1024;
  __shared__ alignas(16) __bf16 As[128 * 64];
  __shared__ alignas(16) __bf16 Bs[128 * 64];
  const int tid = threadIdx.x;
  const int wave = tid >> 6, lane = tid & 63;
  const int wm = wave >> 1, wn = wave & 1;
  const int quad = lane >> 4, l15 = lane & 15;
  const int p0 = blockIdx.y * 128, s0 = blockIdx.x * 128;
  const int srow8 = lane >> 3, sc8 = lane & 7;
  const int sswz = sc8 ^ srow8;

  floatx4 acc[4][4] = {};

  for (int kb = 0; kb < K; kb += 64) {
    __syncthreads();
#pragma unroll
    for (int t = 0; t < 4; t++) {
      int rbase = (wave * 4 + t) * 8;
      int row = rbase + srow8;
      load_lds16(WT + (size_t)(p0 + row) * K + kb + sswz * 8, As + rbase * 64);
      load_lds16(X + (size_t)(s0 + row) * K + kb + sswz * 8, Bs + rbase * 64);
    }
    __syncthreads();
#pragma unroll
    for (int ks = 0; ks < 2; ks++) {
      bf16x8 af[4], bfv[4];
#pragma unroll
      for (int t = 0; t < 4; t++) {
        int ra = wm * 64 + t * 16 + l15;
        int rb = wn * 64 + t * 16 + l15;
        int ch = (ks * 4 + quad) ^ (l15 & 7);
        af[t]  = *(const bf16x8*)(As + ra * 64 + ch * 8);
        bfv[t] = *(const bf16x8*)(Bs + rb * 64 + ch * 8);
      }
#pragma unroll
      for (int mi = 0; mi < 4; mi++)
#pragma unroll
        for (int ni = 0; ni < 4; ni++)
          acc[mi][ni] = mfma16(af[mi], bfv[ni], acc[mi][ni]);
    }
  }

  const float qscale = (p0 < 1024) ? 0.125f * LOG2E : 1.0f;  // block-uniform
#pragma unroll
  for (int mi = 0; mi < 4; mi++) {
#pragma unroll
    for (int ni = 0; ni < 4; ni++) {
      int pb = p0 + wm * 64 + mi * 16 + quad * 4;  // channel base (mult of 4)
      int s  = s0 + wn * 64 + ni * 16 + l15;       // token
      int b = s >> 11, s2 = s & 2047;
      if (p0 < 2048) {  // q/k: uniform per block
        int part = pb >> 10, h = (pb & 1023) >> 6, dhb = pb & 63;
        bf16x4 o = {(__bf16)((acc[mi][ni][0] + bias[pb]) * qscale),
                    (__bf16)((acc[mi][ni][1] + bias[pb + 1]) * qscale),
                    (__bf16)((acc[mi][ni][2] + bias[pb + 2]) * qscale),
                    (__bf16)((acc[mi][ni][3] + bias[pb + 3]) * qscale)};
        *(bf16x4*)(qk + (size_t)part * 4194304 +
                   ((size_t)((b * 16 + h) * 2048 + s2)) * 64 + dhb) = o;
      } else {  // v -> v^T with per-chunk key permutation
        int h = (pb & 1023) >> 6, dhb = pb & 63;
        int off = s2 & 63, t = off >> 4, qd = (off >> 2) & 3, rr = off & 3;
        int ps2 = (s2 & ~63) | ((t >> 1) * 32 + qd * 8 + (t & 1) * 4 + rr);
#pragma unroll
        for (int r = 0; r < 4; r++)
          vtb[((size_t)((b * 16 + h) * 64 + dhb + r)) * 2048 + ps2] =
              (__bf16)(acc[mi][ni][r] + bias[pb + r]);
      }
    }
  }
}

// ---------------------------------------------------------------------------
// Output projection, 64x128 tile: grid (8, 64) = 512 blocks.  fp32 out + bias.
// ---------------------------------------------------------------------------
__global__ __launch_bounds__(256)
void gemm_proj(const __bf16* __restrict__ A, const __bf16* __restrict__ BT,
               const float* __restrict__ bias, float* __restrict__ Cout, int N) {
  const int K = 1024;
  __shared__ alignas(16) __bf16 As[64 * 64];
  __shared__ alignas(16) __bf16 Bs[128 * 64];
  const int tid = threadIdx.x;
  const int wave = tid >> 6, lane = tid & 63;
  const int wm = wave >> 1, wn = wave & 1;
  const int quad = lane >> 4, l15 = lane & 15;
  const int m0 = blockIdx.y * 64, n0 = blockIdx.x * 128;
  const int srow8 = lane >> 3, sc8 = lane & 7;
  const int sswz = sc8 ^ srow8;

  floatx4 acc[2][4] = {};

  for (int kb = 0; kb < K; kb += 64) {
    __syncthreads();
#pragma unroll
    for (int t = 0; t < 2; t++) {
      int rbase = (wave * 2 + t) * 8;
      load_lds16(A + (size_t)(m0 + rbase + srow8) * K + kb + sswz * 8,
                 As + rbase * 64);
    }
#pragma unroll
    for (int t = 0; t < 4; t++) {
      int rbase = (wave * 4 + t) * 8;
      load_lds16(BT + (size_t)(n0 + rbase + srow8) * K + kb + sswz * 8,
                 Bs + rbase * 64);
    }
    __syncthreads();
#pragma unroll
    for (int ks = 0; ks < 2; ks++) {
      bf16x8 af[2], bfv[4];
      int ch = (ks * 4 + quad) ^ (l15 & 7);
#pragma unroll
      for (int t = 0; t < 2; t++)
        af[t] = *(const bf16x8*)(As + (wm * 32 + t * 16 + l15) * 64 + ch * 8);
#pragma unroll
      for (int t = 0; t < 4; t++)
        bfv[t] = *(const bf16x8*)(Bs + (wn * 64 + t * 16 + l15) * 64 + ch * 8);
#pragma unroll
      for (int mi = 0; mi < 2; mi++)
#pragma unroll
        for (int ni = 0; ni < 4; ni++)
          acc[mi][ni] = mfma16(af[mi], bfv[ni], acc[mi][ni]);
    }
  }

#pragma unroll
  for (int mi = 0; mi < 2; mi++)
#pragma unroll
    for (int ni = 0; ni < 4; ni++) {
      int n = n0 + wn * 64 + ni * 16 + l15;
#pragma unroll
      for (int r = 0; r < 4; r++) {
        int m = m0 + wm * 32 + mi * 16 + quad * 4 + r;
        Cout[(size_t)m * N + n] = acc[mi][ni][r] + bias[n];
      }
    }
}

// ---------------------------------------------------------------------------
// Causal flash attention v11: split-K x4, shuffle-free PV with permuted-V
// 16B A-frag loads.  Block = 4 waves = one 32-q strip; wave w takes chunks
// w, w+4, ...  S^T = K·Q^T (16x16x32): C col(l15)=q, row(quad*4+r)=key.
// O^T = V^T·P^T via 16x16x16: P^T C-layout == B-operand layout, V permuted
// so one 16B load feeds two tile A-frags.  pm==0 (no padding) wave-uniform
// fast path skips all pad-mask VALU.  Q pre-scaled 0.125*LOG2E.
// NO second __launch_bounds__ arg (R4/R7: waves/EU hint -> spills).
// ---------------------------------------------------------------------------
__global__ __launch_bounds__(256)
void flash_attn(const __bf16* __restrict__ q, const __bf16* __restrict__ k,
                const __bf16* __restrict__ vt, const int* __restrict__ amask,
                __bf16* __restrict__ ctx) {
  const int S = 2048;
  __shared__ float mbuf[3][36][64];  // [wave-1][elem][lane], conflict-free
  const int bid = blockIdx.x;
  const int wave = threadIdx.x >> 6, lane = threadIdx.x & 63;
  const int j = 63 - (bid >> 5);               // strip, heaviest first
  const int bh = (bid & 7) * 4 + ((bid >> 3) & 3);
  const int b = bh >> 4, h = bh & 15;
  const int quad = lane >> 4, l15 = lane & 15;
  const int q0 = j * 32;

  const __bf16* qp  = q  + (size_t)bh * S * 64;
  const __bf16* kp0 = k  + (size_t)bh * S * 64;
  const __bf16* vp0 = vt + (size_t)bh * 64 * S;

  bf16x8 qf[2][2];  // [mt][ks]
#pragma unroll
  for (int mt = 0; mt < 2; mt++)
#pragma unroll
    for (int ks = 0; ks < 2; ks++)
      qf[mt][ks] = *(const bf16x8*)(qp + (size_t)(q0 + mt * 16 + l15) * 64 +
                                    ks * 32 + quad * 8);

  float mrun[2] = {-1.0e30f, -1.0e30f}, lrun[2] = {0.0f, 0.0f};
  floatx4 oacc[2][4] = {};  // [mt][dh-tile]; col(l15)=q, row(quad*4+r)=dh
  const int nch = ((q0 + 31) >> 6) + 1;  // 64-key chunks

  for (int c = wave; c < nch; c += 4) {
    const __bf16* kp = kp0 + (size_t)c * 64 * 64;
    floatx4 st[4][2] = {};  // [key-tile][q-tile]; col(l15)=q, row(quad*4+r)=key
#pragma unroll
    for (int ks = 0; ks < 2; ks++) {
      bf16x8 kf[4];
#pragma unroll
      for (int nt = 0; nt < 4; nt++)
        kf[nt] = *(const bf16x8*)(kp + (size_t)(nt * 16 + l15) * 64 +
                                  ks * 32 + quad * 8);
#pragma unroll
      for (int nt = 0; nt < 4; nt++) {
        st[nt][0] = mfma16(kf[nt], qf[0][ks], st[nt][0]);
        st[nt][1] = mfma16(kf[nt], qf[1][ks], st[nt][1]);
      }
    }
    unsigned long long pm = __ballot(amask[b * S + c * 64 + lane] == 0);

    if (pm == 0) {  // no padding (wave-uniform; true for all-ones mask)
      if (c == nch - 1) {
#pragma unroll
        for (int nt = 0; nt < 4; nt++) {
          int keyg = c * 64 + nt * 16 + quad * 4;
#pragma unroll
          for (int r = 0; r < 4; r++)
#pragma unroll
            for (int mt = 0; mt < 2; mt++) {
              bool masked = keyg + r > q0 + mt * 16 + l15;
              st[nt][mt][r] = masked ? MASKVAL : st[nt][mt][r];
            }
        }
      }
    } else {
#pragma unroll
      for (int nt = 0; nt < 4; nt++) {
        int kl = nt * 16 + quad * 4;
        int keyg = c * 64 + kl;
#pragma unroll
        for (int r = 0; r < 4; r++) {
          bool pad = (pm >> (kl + r)) & 1ull;
#pragma unroll
          for (int mt = 0; mt < 2; mt++) {
            bool masked = pad || ((c == nch - 1) &&
                                  (keyg + r > q0 + mt * 16 + l15));
            st[nt][mt][r] = masked ? MASKVAL : st[nt][mt][r];
          }
        }
      }
    }

    // online softmax in log2 domain (per q = l15), tree reductions
    float al[2];
#pragma unroll
    for (int mt = 0; mt < 2; mt++) {
      float m4[4];
#pragma unroll
      for (int nt = 0; nt < 4; nt++)
        m4[nt] = fmaxf(fmaxf(st[nt][mt][0], st[nt][mt][1]),
                       fmaxf(st[nt][mt][2], st[nt][mt][3]));
      float rm = fmaxf(fmaxf(m4[0], m4[1]), fmaxf(m4[2], m4[3]));
      rm = fmaxf(rm, __shfl_xor(rm, 16, 64));
      rm = fmaxf(rm, __shfl_xor(rm, 32, 64));
      float mnew = fmaxf(mrun[mt], rm);
      al[mt] = exp2f(mrun[mt] - mnew);
      mrun[mt] = mnew;
      float s4[4];
#pragma unroll
      for (int nt = 0; nt < 4; nt++) {
        float p0 = exp2f(st[nt][mt][0] - mnew);
        float p1 = exp2f(st[nt][mt][1] - mnew);
        float p2 = exp2f(st[nt][mt][2] - mnew);
        float p3 = exp2f(st[nt][mt][3] - mnew);
        st[nt][mt][0] = p0; st[nt][mt][1] = p1;
        st[nt][mt][2] = p2; st[nt][mt][3] = p3;
        s4[nt] = (p0 + p1) + (p2 + p3);
      }
      float rs = (s4[0] + s4[1]) + (s4[2] + s4[3]);
      rs += __shfl_xor(rs, 16, 64);
      rs += __shfl_xor(rs, 32, 64);
      lrun[mt] = lrun[mt] * al[mt] + rs;
    }

    // rescale O: alpha per q = l15 -> lane-local
#pragma unroll
    for (int mt = 0; mt < 2; mt++)
#pragma unroll
      for (int nd = 0; nd < 4; nd++)
#pragma unroll
        for (int r = 0; r < 4; r++) oacc[mt][nd][r] *= al[mt];

    // pack P tiles (B-operand == C-layout)
    bf16x4 pB[4][2];
#pragma unroll
    for (int nt = 0; nt < 4; nt++)
#pragma unroll
      for (int mt = 0; mt < 2; mt++) {
        bf16x4 pk = {(__bf16)st[nt][mt][0], (__bf16)st[nt][mt][1],
                     (__bf16)st[nt][mt][2], (__bf16)st[nt][mt][3]};
        pB[nt][mt] = pk;
      }

    // O^T += V^T P^T ; one 16B V load feeds tiles 2tp and 2tp+1
#pragma unroll
    for (int tp = 0; tp < 2; tp++) {
      const __bf16* vp = vp0 + c * 64 + tp * 32 + quad * 8;
#pragma unroll
      for (int nd = 0; nd < 4; nd++) {
        bf16x8 v8 = *(const bf16x8*)(vp + (size_t)(nd * 16 + l15) * S);
        bf16x4 vA0 = {v8[0], v8[1], v8[2], v8[3]};
        bf16x4 vA1 = {v8[4], v8[5], v8[6], v8[7]};
        oacc[0][nd] = mfma_pv(vA0, pB[2 * tp][0], oacc[0][nd]);
        oacc[1][nd] = mfma_pv(vA0, pB[2 * tp][1], oacc[1][nd]);
        oacc[0][nd] = mfma_pv(vA1, pB[2 * tp + 1][0], oacc[0][nd]);
        oacc[1][nd] = mfma_pv(vA1, pB[2 * tp + 1][1], oacc[1][nd]);
      }
    }
  }

  // ---- split-K merge: waves 1-3 publish (O, m, l); wave 0 combines ----
  if (wave != 0) {
    int w = wave - 1;
#pragma unroll
    for (int mt = 0; mt < 2; mt++)
#pragma unroll
      for (int nd = 0; nd < 4; nd++)
#pragma unroll
        for (int r = 0; r < 4; r++)
          mbuf[w][(mt * 4 + nd) * 4 + r][lane] = oacc[mt][nd][r];
#pragma unroll
    for (int mt = 0; mt < 2; mt++) {
      mbuf[w][32 + mt][lane] = mrun[mt];
      mbuf[w][34 + mt][lane] = lrun[mt];
    }
  }
  __syncthreads();
  if (wave != 0) return;

  // combine factors per q = l15 (lane-local; log2 domain)
  float fw[3][2], f0[2], lstar[2];
#pragma unroll
  for (int mt = 0; mt < 2; mt++) {
    float mw0 = mbuf[0][32 + mt][lane], lw0 = mbuf[0][34 + mt][lane];
    float mw1 = mbuf[1][32 + mt][lane], lw1 = mbuf[1][34 + mt][lane];
    float mw2 = mbuf[2][32 + mt][lane], lw2 = mbuf[2][34 + mt][lane];
    float mstar = fmaxf(fmaxf(mrun[mt], mw0), fmaxf(mw1, mw2));
    f0[mt] = exp2f(mrun[mt] - mstar);
    fw[0][mt] = exp2f(mw0 - mstar);
    fw[1][mt] = exp2f(mw1 - mstar);
    fw[2][mt] = exp2f(mw2 - mstar);
    lstar[mt] = f0[mt] * lrun[mt] + fw[0][mt] * lw0 + fw[1][mt] * lw1 +
                fw[2][mt] * lw2;
    lstar[mt] = 1.0f / lstar[mt];
  }

  // epilogue: lane l15 = q, rows quad*4+r = dh -> packed b64 stores
#pragma unroll
  for (int mt = 0; mt < 2; mt++) {
    int s = q0 + mt * 16 + l15;
#pragma unroll
    for (int nd = 0; nd < 4; nd++) {
      float ov[4];
#pragma unroll
      for (int r = 0; r < 4; r++) {
        float v = f0[mt] * oacc[mt][nd][r];
#pragma unroll
        for (int w = 0; w < 3; w++)
          v += fw[w][mt] * mbuf[w][(mt * 4 + nd) * 4 + r][lane];
        ov[r] = v * lstar[mt];
      }
      bf16x4 o = {(__bf16)ov[0], (__bf16)ov[1], (__bf16)ov[2], (__bf16)ov[3]};
      *(bf16x4*)(ctx + ((size_t)(b * 2048 + s)) * 1024 + h * 64 + nd * 16 +
                 quad * 4) = o;
    }
  }
}

// ---------------------------------------------------------------------------
extern "C" void kernel_launch(void* const* d_in, const int* in_sizes, int n_in,
                              void* d_out, int out_size, void* d_ws, size_t ws_size,
                              hipStream_t stream) {
  const float* x  = (const float*)d_in[0];
  const int*   am = (const int*)d_in[1];
  const float* Wq = (const float*)d_in[2];
  const float* bq = (const float*)d_in[3];
  const float* Aq = (const float*)d_in[4];
  const float* Bq = (const float*)d_in[5];
  const float* Wp = (const float*)d_in[6];
  const float* bp = (const float*)d_in[7];
  const float* Ap = (const float*)d_in[8];
  const float* Bp = (const float*)d_in[9];

  __bf16* wqkvT = (__bf16*)d_ws;                       // [3072][1024]
  __bf16* wpT   = wqkvT + (size_t)3072 * 1024;         // [1024][1024]
  __bf16* xbf   = wpT   + (size_t)1024 * 1024;         // [4096][1024]
  __bf16* qbuf  = xbf   + (size_t)4096 * 1024;         // [2][16][2048][64] (+kbuf)
  __bf16* vtbuf = qbuf  + (size_t)2 * 4194304;         // [2][16][64][2048] permuted
  __bf16* ctxb  = vtbuf + (size_t)4194304;             // [4096][1024]

  fold_wt2<<<dim3(64, 16), 256, 0, stream>>>(Wq, Aq, Bq, wqkvT,
                                             Wp, Ap, Bp, wpT);
  cast_x<<<4096, 256, 0, stream>>>(x, xbf);

  gemm_qkv<<<dim3(32, 24), 256, 0, stream>>>(wqkvT, xbf, bq, qbuf, vtbuf);
  flash_attn<<<2048, 256, 0, stream>>>(qbuf, qbuf + 4194304, vtbuf, am, ctxb);
  gemm_proj<<<dim3(8, 64), 256, 0, stream>>>(ctxb, wpT, bp, (float*)d_out, 1024);
}